// Round 5
// baseline (116.374 us; speedup 1.0000x reference)
//
#include <hip/hip_runtime.h>
#include <stdint.h>

#define B_ 32
#define N_ 4096
#define C_ 256
#define S_ 7
#define D_ 64
#define H_ 128
#define NB_ 32     // n-chunks per batch in attention
#define NC_ 128    // chunk size (NB_*NC_ == N_)

typedef __attribute__((ext_vector_type(8))) short short8;
typedef __attribute__((ext_vector_type(4))) float f32x4;

static __device__ __forceinline__ unsigned short f2bf(float f) {
  unsigned int u = __float_as_uint(f);
  unsigned int r = u + 0x7FFFu + ((u >> 16) & 1u);   // RNE
  return (unsigned short)(r >> 16);
}
static __device__ __forceinline__ float bf2f(unsigned short h) {
  return __uint_as_float(((unsigned int)h) << 16);
}

// ---------------- prep: pack Wkv into MFMA B-fragments + init slots/q0 -----
// pack frag f = nf*8 + ks. lane l, elems j=0..7: W[e][c], e = nf*16+(l&15),
// c = ks*32 + (l>>4)*8 + j.
__global__ __launch_bounds__(256) void prep_kernel(
    const float* __restrict__ Wkv, uint4* __restrict__ Wbf,
    const float* __restrict__ slots, const float* __restrict__ g_sl,
    const float* __restrict__ b_sl, const float* __restrict__ Wq,
    float* __restrict__ sl_ws, float* __restrict__ q_ws) {
  __shared__ float hl[64];
  if (blockIdx.x < 16) {
    const int t = blockIdx.x * 256 + threadIdx.x;   // 0..4095
    const int f = t >> 6, lane = t & 63;
    const int e = ((f >> 3) << 4) + (lane & 15);
    const int c = ((f & 7) << 5) + ((lane >> 4) << 3);
    const float* src = Wkv + e * 256 + c;
    uint4 o;
    o.x = f2bf(src[0]) | ((unsigned)f2bf(src[1]) << 16);
    o.y = f2bf(src[2]) | ((unsigned)f2bf(src[3]) << 16);
    o.z = f2bf(src[4]) | ((unsigned)f2bf(src[5]) << 16);
    o.w = f2bf(src[6]) | ((unsigned)f2bf(src[7]) << 16);
    Wbf[t] = o;
  } else {
    const int bs = blockIdx.x - 16;                 // 0..223
    const int tid = threadIdx.x;
    if (tid < 64) {
      const float v = slots[bs * 64 + tid];
      sl_ws[bs * 64 + tid] = v;
      float su = v, sq = v * v;
#pragma unroll
      for (int o = 32; o >= 1; o >>= 1) { su += __shfl_xor(su, o); sq += __shfl_xor(sq, o); }
      const float mean = su * (1.f / 64.f);
      const float rstd = rsqrtf(fmaxf(sq * (1.f / 64.f) - mean * mean, 0.f) + 1e-5f);
      hl[tid] = (v - mean) * rstd * g_sl[tid] + b_sl[tid];
    }
    __syncthreads();
    if (tid < 64) {
      float acc = 0.f;
      const float* wq = Wq + tid * 64;
#pragma unroll 8
      for (int d = 0; d < 64; ++d) acc += hl[d] * wq[d];
      q_ws[bs * 64 + tid] = acc;
    }
  }
}

// ---------------- K_KV: fused LayerNorm(x) + GEMM -> kv (bf16) -------------
// block: 256 thr (4 waves, 2x2 wave grid), tile 64 rows x 128 cols, K=256.
// LDS 32 KiB -> 4 blocks/CU.
__global__ __launch_bounds__(256, 4) void kv_kernel(
    const float* __restrict__ x, const float* __restrict__ g_in,
    const float* __restrict__ b_in, const uint4* __restrict__ Wbf,
    unsigned short* __restrict__ kv) {
  __shared__ __align__(16) char lds[32768];
  const int tid = threadIdx.x;
  const int lane = tid & 63, w = tid >> 6;
  const int wm = w >> 1, wn = w & 1;
  const size_t rowbase = (size_t)blockIdx.x * 64;

  // LN phase: wave w owns rows w*16..w*16+15, 4 rows/iter via 16-lane groups.
  {
    const int q = lane & 15, grp = lane >> 4;
    float4 gv[4], bv[4];
#pragma unroll
    for (int j = 0; j < 4; ++j) {
      gv[j] = *(const float4*)(g_in + j * 64 + q * 4);
      bv[j] = *(const float4*)(b_in + j * 64 + q * 4);
    }
#pragma unroll
    for (int i = 0; i < 4; ++i) {
      const int r = w * 16 + i * 4 + grp;
      const float* xrow = x + (rowbase + r) * 256;
      float4 xv[4];
#pragma unroll
      for (int j = 0; j < 4; ++j) xv[j] = *(const float4*)(xrow + j * 64 + q * 4);
      float su = 0.f, sq = 0.f;
#pragma unroll
      for (int j = 0; j < 4; ++j) {
        su += xv[j].x + xv[j].y + xv[j].z + xv[j].w;
        sq += xv[j].x * xv[j].x + xv[j].y * xv[j].y + xv[j].z * xv[j].z + xv[j].w * xv[j].w;
      }
#pragma unroll
      for (int o = 8; o >= 1; o >>= 1) { su += __shfl_xor(su, o); sq += __shfl_xor(sq, o); }
      const float mean = su * (1.f / 256.f);
      const float rstd = rsqrtf(fmaxf(sq * (1.f / 256.f) - mean * mean, 0.f) + 1e-5f);
#pragma unroll
      for (int j = 0; j < 4; ++j) {
        const float n0 = (xv[j].x - mean) * rstd * gv[j].x + bv[j].x;
        const float n1 = (xv[j].y - mean) * rstd * gv[j].y + bv[j].y;
        const float n2 = (xv[j].z - mean) * rstd * gv[j].z + bv[j].z;
        const float n3 = (xv[j].w - mean) * rstd * gv[j].w + bv[j].w;
        uint2 pk;
        pk.x = (unsigned)f2bf(n0) | ((unsigned)f2bf(n1) << 16);
        pk.y = (unsigned)f2bf(n2) | ((unsigned)f2bf(n3) << 16);
        const int addr = (r * 512 + j * 128 + q * 8) ^ ((r & 7) << 4);   // XOR swizzle
        *(uint2*)(lds + addr) = pk;
      }
    }
  }
  __syncthreads();

  f32x4 acc[2][4];
#pragma unroll
  for (int m = 0; m < 2; ++m)
#pragma unroll
    for (int n = 0; n < 4; ++n) acc[m][n] = (f32x4){0.f, 0.f, 0.f, 0.f};

#pragma unroll
  for (int ks = 0; ks < 8; ++ks) {
    short8 a[2];
#pragma unroll
    for (int m = 0; m < 2; ++m) {
      const int row = wm * 32 + m * 16 + (lane & 15);
      const int addr = (row * 512 + ks * 64 + ((lane >> 4) << 4)) ^ ((row & 7) << 4);
      a[m] = *(const short8*)(lds + addr);
    }
#pragma unroll
    for (int n = 0; n < 4; ++n) {
      union { uint4 u; short8 s; } wb;
      wb.u = Wbf[((wn * 4 + n) * 8 + ks) * 64 + lane];
#pragma unroll
      for (int m = 0; m < 2; ++m)
        acc[m][n] = __builtin_amdgcn_mfma_f32_16x16x32_bf16(a[m], wb.s, acc[m][n], 0, 0, 0);
    }
  }
  __syncthreads();

  // epilogue: C/D layout col=lane&15, row=(lane>>4)*4+j  -> padded LDS -> coalesced store
#pragma unroll
  for (int m = 0; m < 2; ++m)
#pragma unroll
    for (int n = 0; n < 4; ++n) {
      const int row0 = wm * 32 + m * 16 + ((lane >> 4) << 2);
      const int col = wn * 64 + n * 16 + (lane & 15);
#pragma unroll
      for (int j = 0; j < 4; ++j)
        *(unsigned short*)(lds + (row0 + j) * 264 + col * 2) = f2bf(acc[m][n][j]);
    }
  __syncthreads();
#pragma unroll
  for (int i = 0; i < 16; ++i) {
    const int r = w * 16 + i;
    const unsigned int vv = *(const unsigned int*)(lds + r * 264 + lane * 4);
    *(unsigned int*)((char*)kv + (rowbase + r) * 256 + lane * 4) = vv;
  }
}

// ---------------- K2: fused logits/softmax(S)/weighted-sum partials --------
// 256 threads (4 waves), chunk = 128 n. phase1a: 2 threads per n (j-halves).
// phase1b: combine + proper softmax over s. phase2: wave owns 32 nn, all 7 s.
// NOTE: every guard/loop must cover its range with 256 threads (r2/r4 bug!).
__global__ __launch_bounds__(256) void attn_kernel(
    const unsigned short* __restrict__ kv, const float* __restrict__ q_ws,
    float* __restrict__ numer, float* __restrict__ denom) {
  __shared__ float qs[S_][64];
  __shared__ float lgp[S_][256];
  __shared__ float wl[S_][NC_];
  __shared__ float part[4][S_][64];
  __shared__ float partd[4][S_];
  const int b = blockIdx.y, cb = blockIdx.x;
  const int tid = threadIdx.x;
  for (int p = tid; p < S_ * 64; p += 256) qs[p >> 6][p & 63] = q_ws[b * S_ * 64 + p];
  __syncthreads();

  // phase 1a: thread (nn, jh) computes half of the 7 logits for n = cb*128+nn
  {
    const int nn = tid & 127, jh = tid >> 7;
    const int n = cb * NC_ + nn;
    const unsigned short* krow = kv + ((size_t)(b * N_ + n)) * 128 + jh * 32;
    float lg[S_];
#pragma unroll
    for (int s = 0; s < S_; ++s) lg[s] = 0.f;
#pragma unroll
    for (int j = 0; j < 4; ++j) {
      const uint4 kk = *(const uint4*)(krow + j * 8);
      float kf[8];
      kf[0] = __uint_as_float(kk.x << 16); kf[1] = __uint_as_float(kk.x & 0xffff0000u);
      kf[2] = __uint_as_float(kk.y << 16); kf[3] = __uint_as_float(kk.y & 0xffff0000u);
      kf[4] = __uint_as_float(kk.z << 16); kf[5] = __uint_as_float(kk.z & 0xffff0000u);
      kf[6] = __uint_as_float(kk.w << 16); kf[7] = __uint_as_float(kk.w & 0xffff0000u);
#pragma unroll
      for (int s = 0; s < S_; ++s) {
        const float4 qa = *(const float4*)&qs[s][jh * 32 + j * 8];
        const float4 qb = *(const float4*)&qs[s][jh * 32 + j * 8 + 4];
        lg[s] += qa.x * kf[0] + qa.y * kf[1] + qa.z * kf[2] + qa.w * kf[3]
               + qb.x * kf[4] + qb.y * kf[5] + qb.z * kf[6] + qb.w * kf[7];
      }
    }
#pragma unroll
    for (int s = 0; s < S_; ++s) lgp[s][jh * 128 + nn] = lg[s];
  }
  __syncthreads();

  // phase 1b: combine halves, scale, proper softmax over s
  if (tid < NC_) {
    float lg[S_], mx = -1e30f;
#pragma unroll
    for (int s = 0; s < S_; ++s) {
      const float t = (lgp[s][tid] + lgp[s][128 + tid]) * 0.125f;
      lg[s] = t; mx = fmaxf(mx, t);
    }
    float es[S_], sum = 0.f;
#pragma unroll
    for (int s = 0; s < S_; ++s) { es[s] = __expf(lg[s] - mx); sum += es[s]; }
    const float inv = 1.f / sum;
#pragma unroll
    for (int s = 0; s < S_; ++s) wl[s][tid] = es[s] * inv;
  }
  __syncthreads();

  // phase 2: wave wv accumulates its own 32 nn for ALL 7 s (v read once)
  const int wv = tid >> 6, ln = tid & 63;
  {
    const unsigned short* vptr = kv + ((size_t)(b * N_ + cb * NC_ + wv * 32)) * 128 + 64 + ln;
    float acc[S_], ds[S_];
#pragma unroll
    for (int s = 0; s < S_; ++s) { acc[s] = 0.f; ds[s] = 0.f; }
#pragma unroll 8
    for (int nn = 0; nn < 32; ++nn) {
      const float vv = bf2f(vptr[(size_t)nn * 128]);
#pragma unroll
      for (int s = 0; s < S_; ++s) {
        const float wgt = wl[s][wv * 32 + nn];
        acc[s] += wgt * vv;
        ds[s] += wgt;
      }
    }
#pragma unroll
    for (int s = 0; s < S_; ++s) part[wv][s][ln] = acc[s];
    if (ln == 0) {
#pragma unroll
      for (int s = 0; s < S_; ++s) partd[wv][s] = ds[s];
    }
  }
  __syncthreads();

  // cross-wave reduce -> global partials (448 outputs, 256 threads -> LOOP)
  for (int p = tid; p < S_ * 64; p += 256) {
    const int s = p >> 6, d = p & 63;
    const float sum4 = part[0][s][d] + part[1][s][d] + part[2][s][d] + part[3][s][d];
    numer[((size_t)(b * NB_ + cb) * S_ + s) * 64 + d] = sum4;
  }
  if (tid < S_) {
    denom[(b * NB_ + cb) * S_ + tid] =
        partd[0][tid] + partd[1][tid] + partd[2][tid] + partd[3][tid];
  }
}

// ---------------- K3: reduce partials + GRU + MLP + next q -----------------
__global__ __launch_bounds__(192) void update_kernel(
    const float* __restrict__ numer, const float* __restrict__ denom,
    const float* __restrict__ Wih, const float* __restrict__ Whh,
    const float* __restrict__ bih, const float* __restrict__ bhh,
    const float* __restrict__ g_mlp, const float* __restrict__ b_mlp,
    const float* __restrict__ W1, const float* __restrict__ b1,
    const float* __restrict__ W2, const float* __restrict__ b2,
    const float* __restrict__ g_sl, const float* __restrict__ b_sl,
    const float* __restrict__ Wq,
    float* __restrict__ sl_ws, float* __restrict__ q_ws,
    float* __restrict__ d_out, const int write_out) {
  const int bs = blockIdx.x;
  const int b = bs / S_, s = bs % S_;
  const int tid = threadIdx.x;
  __shared__ float attn[64], sl[64], gi[192], gh[192], hn[64], h1[128], sn[64], tmp[64];

  if (tid < 64) {
    float acc = 0.f, dd = 0.f;
#pragma unroll 8
    for (int blk = 0; blk < NB_; ++blk) {
      acc += numer[((size_t)(b * NB_ + blk) * S_ + s) * 64 + tid];
      dd += denom[(b * NB_ + blk) * S_ + s];
    }
    attn[tid] = acc / (dd + 1e-12f);
    sl[tid] = sl_ws[bs * 64 + tid];
  }
  __syncthreads();
  {
    float a = bih[tid], h = bhh[tid];
    const float* wi = Wih + tid * 64;
    const float* wh = Whh + tid * 64;
#pragma unroll 8
    for (int d = 0; d < 64; ++d) { a += attn[d] * wi[d]; h += sl[d] * wh[d]; }
    gi[tid] = a; gh[tid] = h;
  }
  __syncthreads();
  if (tid < 64) {
    const float r = 1.f / (1.f + __expf(-(gi[tid] + gh[tid])));
    const float z = 1.f / (1.f + __expf(-(gi[64 + tid] + gh[64 + tid])));
    const float nn = tanhf(gi[128 + tid] + r * gh[128 + tid]);
    sn[tid] = (1.f - z) * nn + z * sl[tid];
  }
  __syncthreads();
  if (tid < 64) {  // LN(sn) with g_mlp/b_mlp
    const float v = sn[tid];
    float su = v, sq = v * v;
#pragma unroll
    for (int o = 32; o >= 1; o >>= 1) { su += __shfl_xor(su, o); sq += __shfl_xor(sq, o); }
    const float mean = su * (1.f / 64.f);
    const float rstd = rsqrtf(fmaxf(sq * (1.f / 64.f) - mean * mean, 0.f) + 1e-5f);
    hn[tid] = (v - mean) * rstd * g_mlp[tid] + b_mlp[tid];
  }
  __syncthreads();
  if (tid < 128) {
    float a = b1[tid];
    const float* w1r = W1 + tid * 64;
#pragma unroll 8
    for (int d = 0; d < 64; ++d) a += hn[d] * w1r[d];
    h1[tid] = fmaxf(a, 0.f);
  }
  __syncthreads();
  if (tid < 64) {
    float a = b2[tid];
    const float* w2r = W2 + tid * 128;
#pragma unroll 8
    for (int h = 0; h < 128; ++h) a += h1[h] * w2r[h];
    const float o = sn[tid] + a;
    sl_ws[bs * 64 + tid] = o;
    if (write_out) d_out[bs * 64 + tid] = o;
    tmp[tid] = o;
  }
  __syncthreads();
  if (tid < 64) {  // LN(new slots) with g_sl/b_sl for next q
    const float v = tmp[tid];
    float su = v, sq = v * v;
#pragma unroll
    for (int o = 32; o >= 1; o >>= 1) { su += __shfl_xor(su, o); sq += __shfl_xor(sq, o); }
    const float mean = su * (1.f / 64.f);
    const float rstd = rsqrtf(fmaxf(sq * (1.f / 64.f) - mean * mean, 0.f) + 1e-5f);
    hn[tid] = (v - mean) * rstd * g_sl[tid] + b_sl[tid];
  }
  __syncthreads();
  if (tid < 64) {
    float a = 0.f;
    const float* wq = Wq + tid * 64;
#pragma unroll 8
    for (int d = 0; d < 64; ++d) a += hn[d] * wq[d];
    q_ws[bs * 64 + tid] = a;
  }
}

extern "C" void kernel_launch(void* const* d_in, const int* in_sizes, int n_in,
                              void* d_out, int out_size, void* d_ws, size_t ws_size,
                              hipStream_t stream) {
  const float* x = (const float*)d_in[0];
  const float* slots = (const float*)d_in[1];
  const float* g_in = (const float*)d_in[2];
  const float* b_in = (const float*)d_in[3];
  const float* g_sl = (const float*)d_in[4];
  const float* b_sl = (const float*)d_in[5];
  const float* g_mlp = (const float*)d_in[6];
  const float* b_mlp = (const float*)d_in[7];
  const float* Wq = (const float*)d_in[8];
  const float* Wkv = (const float*)d_in[9];
  const float* Wih = (const float*)d_in[10];
  const float* Whh = (const float*)d_in[11];
  const float* bih = (const float*)d_in[12];
  const float* bhh = (const float*)d_in[13];
  const float* W1 = (const float*)d_in[14];
  const float* b1 = (const float*)d_in[15];
  const float* W2 = (const float*)d_in[16];
  const float* b2 = (const float*)d_in[17];

  char* ws = (char*)d_ws;
  size_t off = 0;
  unsigned short* kv = (unsigned short*)(ws + off); off += (size_t)B_ * N_ * 128 * 2;  // 32 MB
  uint4* Wbf = (uint4*)(ws + off); off += 65536;
  float* q_ws = (float*)(ws + off); off += (size_t)B_ * S_ * D_ * 4;
  float* sl_ws = (float*)(ws + off); off += (size_t)B_ * S_ * D_ * 4;
  float* numer = (float*)(ws + off); off += (size_t)B_ * NB_ * S_ * D_ * 4;
  float* denom = (float*)(ws + off); off += (size_t)B_ * NB_ * S_ * 4;

  prep_kernel<<<16 + B_ * S_, 256, 0, stream>>>(Wkv, Wbf, slots, g_sl, b_sl, Wq, sl_ws, q_ws);
  kv_kernel<<<(B_ * N_) / 64, 256, 0, stream>>>(x, g_in, b_in, Wbf, kv);
  for (int it = 0; it < 3; ++it) {
    attn_kernel<<<dim3(NB_, B_), 256, 0, stream>>>(kv, q_ws, numer, denom);
    update_kernel<<<B_ * S_, 192, 0, stream>>>(numer, denom, Wih, Whh, bih, bhh,
                                               g_mlp, b_mlp, W1, b1, W2, b2, g_sl, b_sl, Wq,
                                               sl_ws, q_ws, (float*)d_out, it == 2 ? 1 : 0);
  }
}

// Round 6
// 115.280 us; speedup vs baseline: 1.0095x; 1.0095x over previous
//
#include <hip/hip_runtime.h>
#include <stdint.h>

#define B_ 32
#define N_ 4096
#define C_ 256
#define S_ 7
#define D_ 64
#define H_ 128
#define NB_ 16     // n-chunks per batch in attention
#define NC_ 256    // chunk size (NB_*NC_ == N_)

typedef __attribute__((ext_vector_type(8))) short short8;
typedef __attribute__((ext_vector_type(4))) float f32x4;

static __device__ __forceinline__ unsigned short f2bf(float f) {
  unsigned int u = __float_as_uint(f);
  unsigned int r = u + 0x7FFFu + ((u >> 16) & 1u);   // RNE
  return (unsigned short)(r >> 16);
}
static __device__ __forceinline__ float bf2f(unsigned short h) {
  return __uint_as_float(((unsigned int)h) << 16);
}

// ---------------- prep: pack Wkv into MFMA B-fragments + init slots/q0 -----
__global__ __launch_bounds__(256) void prep_kernel(
    const float* __restrict__ Wkv, uint4* __restrict__ Wbf,
    const float* __restrict__ slots, const float* __restrict__ g_sl,
    const float* __restrict__ b_sl, const float* __restrict__ Wq,
    float* __restrict__ sl_ws, float* __restrict__ q_ws) {
  __shared__ float hl[64];
  if (blockIdx.x < 16) {
    const int t = blockIdx.x * 256 + threadIdx.x;   // 0..4095
    const int f = t >> 6, lane = t & 63;
    const int e = ((f >> 3) << 4) + (lane & 15);
    const int c = ((f & 7) << 5) + ((lane >> 4) << 3);
    const float* src = Wkv + e * 256 + c;
    uint4 o;
    o.x = f2bf(src[0]) | ((unsigned)f2bf(src[1]) << 16);
    o.y = f2bf(src[2]) | ((unsigned)f2bf(src[3]) << 16);
    o.z = f2bf(src[4]) | ((unsigned)f2bf(src[5]) << 16);
    o.w = f2bf(src[6]) | ((unsigned)f2bf(src[7]) << 16);
    Wbf[t] = o;
  } else {
    const int bs = blockIdx.x - 16;                 // 0..223
    const int tid = threadIdx.x;
    if (tid < 64) {
      const float v = slots[bs * 64 + tid];
      sl_ws[bs * 64 + tid] = v;
      float su = v, sq = v * v;
#pragma unroll
      for (int o = 32; o >= 1; o >>= 1) { su += __shfl_xor(su, o); sq += __shfl_xor(sq, o); }
      const float mean = su * (1.f / 64.f);
      const float rstd = rsqrtf(fmaxf(sq * (1.f / 64.f) - mean * mean, 0.f) + 1e-5f);
      hl[tid] = (v - mean) * rstd * g_sl[tid] + b_sl[tid];
    }
    __syncthreads();
    if (tid < 64) {
      float acc = 0.f;
      const float* wq = Wq + tid * 64;
#pragma unroll 8
      for (int d = 0; d < 64; ++d) acc += hl[d] * wq[d];
      q_ws[bs * 64 + tid] = acc;
    }
  }
}

// ---------------- K_KV: fused LayerNorm(x) + GEMM -> kv (bf16) -------------
// EXACT round-3 version (proven): unroll 2 on LN loop, 32 KiB LDS, 4 blk/CU.
__global__ __launch_bounds__(256, 4) void kv_kernel(
    const float* __restrict__ x, const float* __restrict__ g_in,
    const float* __restrict__ b_in, const uint4* __restrict__ Wbf,
    unsigned short* __restrict__ kv) {
  __shared__ __align__(16) char lds[32768];
  const int tid = threadIdx.x;
  const int lane = tid & 63, w = tid >> 6;
  const int wm = w >> 1, wn = w & 1;
  const size_t rowbase = (size_t)blockIdx.x * 64;

  {
    const int q = lane & 15, grp = lane >> 4;
    float4 gv[4], bv[4];
#pragma unroll
    for (int j = 0; j < 4; ++j) {
      gv[j] = *(const float4*)(g_in + j * 64 + q * 4);
      bv[j] = *(const float4*)(b_in + j * 64 + q * 4);
    }
#pragma unroll 2
    for (int i = 0; i < 4; ++i) {
      const int r = w * 16 + i * 4 + grp;
      const float* xrow = x + (rowbase + r) * 256;
      float4 xv[4];
#pragma unroll
      for (int j = 0; j < 4; ++j) xv[j] = *(const float4*)(xrow + j * 64 + q * 4);
      float su = 0.f, sq = 0.f;
#pragma unroll
      for (int j = 0; j < 4; ++j) {
        su += xv[j].x + xv[j].y + xv[j].z + xv[j].w;
        sq += xv[j].x * xv[j].x + xv[j].y * xv[j].y + xv[j].z * xv[j].z + xv[j].w * xv[j].w;
      }
#pragma unroll
      for (int o = 8; o >= 1; o >>= 1) { su += __shfl_xor(su, o); sq += __shfl_xor(sq, o); }
      const float mean = su * (1.f / 256.f);
      const float rstd = rsqrtf(fmaxf(sq * (1.f / 256.f) - mean * mean, 0.f) + 1e-5f);
#pragma unroll
      for (int j = 0; j < 4; ++j) {
        const float n0 = (xv[j].x - mean) * rstd * gv[j].x + bv[j].x;
        const float n1 = (xv[j].y - mean) * rstd * gv[j].y + bv[j].y;
        const float n2 = (xv[j].z - mean) * rstd * gv[j].z + bv[j].z;
        const float n3 = (xv[j].w - mean) * rstd * gv[j].w + bv[j].w;
        uint2 pk;
        pk.x = (unsigned)f2bf(n0) | ((unsigned)f2bf(n1) << 16);
        pk.y = (unsigned)f2bf(n2) | ((unsigned)f2bf(n3) << 16);
        const int addr = (r * 512 + j * 128 + q * 8) ^ ((r & 7) << 4);   // XOR swizzle
        *(uint2*)(lds + addr) = pk;
      }
    }
  }
  __syncthreads();

  f32x4 acc[2][4];
#pragma unroll
  for (int m = 0; m < 2; ++m)
#pragma unroll
    for (int n = 0; n < 4; ++n) acc[m][n] = (f32x4){0.f, 0.f, 0.f, 0.f};

#pragma unroll
  for (int ks = 0; ks < 8; ++ks) {
    short8 a[2];
#pragma unroll
    for (int m = 0; m < 2; ++m) {
      const int row = wm * 32 + m * 16 + (lane & 15);
      const int addr = (row * 512 + ks * 64 + ((lane >> 4) << 4)) ^ ((row & 7) << 4);
      a[m] = *(const short8*)(lds + addr);
    }
#pragma unroll
    for (int n = 0; n < 4; ++n) {
      union { uint4 u; short8 s; } wb;
      wb.u = Wbf[((wn * 4 + n) * 8 + ks) * 64 + lane];
#pragma unroll
      for (int m = 0; m < 2; ++m)
        acc[m][n] = __builtin_amdgcn_mfma_f32_16x16x32_bf16(a[m], wb.s, acc[m][n], 0, 0, 0);
    }
  }
  __syncthreads();

#pragma unroll
  for (int m = 0; m < 2; ++m)
#pragma unroll
    for (int n = 0; n < 4; ++n) {
      const int row0 = wm * 32 + m * 16 + ((lane >> 4) << 2);
      const int col = wn * 64 + n * 16 + (lane & 15);
#pragma unroll
      for (int j = 0; j < 4; ++j)
        *(unsigned short*)(lds + (row0 + j) * 264 + col * 2) = f2bf(acc[m][n][j]);
    }
  __syncthreads();
#pragma unroll
  for (int i = 0; i < 16; ++i) {
    const int r = w * 16 + i;
    const unsigned int vv = *(const unsigned int*)(lds + r * 264 + lane * 4);
    *(unsigned int*)((char*)kv + (rowbase + r) * 256 + lane * 4) = vv;
  }
}

// ---------------- K2: fused logits/softmax(S)/weighted-sum partials --------
// 256 threads (4 waves), chunk = 256 n. phase1: thread = one full n, inline
// softmax; denom wave-reduced here (42 shfl) instead of 448 adds in phase2.
// phase2: wave owns 64 nn; 2 nn/iter with uniform float2 wl reads.
__global__ __launch_bounds__(256) void attn_kernel(
    const unsigned short* __restrict__ kv, const float* __restrict__ q_ws,
    float* __restrict__ numer, float* __restrict__ denom) {
  __shared__ float qs[S_][64];
  __shared__ float wl[S_][NC_];
  __shared__ float part[4][S_][64];
  __shared__ float partd[4][S_];
  const int b = blockIdx.y, cb = blockIdx.x;
  const int tid = threadIdx.x;
  const int wv = tid >> 6, ln = tid & 63;
  for (int p = tid; p < S_ * 64; p += 256) qs[p >> 6][p & 63] = q_ws[b * S_ * 64 + p];
  __syncthreads();

  // phase 1: thread = one n (all 256 threads active)
  {
    const int n = cb * NC_ + tid;
    const unsigned short* krow = kv + ((size_t)(b * N_ + n)) * 128;
    float lg[S_];
#pragma unroll
    for (int s = 0; s < S_; ++s) lg[s] = 0.f;
#pragma unroll
    for (int j = 0; j < 8; ++j) {
      const uint4 kk = *(const uint4*)(krow + j * 8);
      float kf[8];
      kf[0] = __uint_as_float(kk.x << 16); kf[1] = __uint_as_float(kk.x & 0xffff0000u);
      kf[2] = __uint_as_float(kk.y << 16); kf[3] = __uint_as_float(kk.y & 0xffff0000u);
      kf[4] = __uint_as_float(kk.z << 16); kf[5] = __uint_as_float(kk.z & 0xffff0000u);
      kf[6] = __uint_as_float(kk.w << 16); kf[7] = __uint_as_float(kk.w & 0xffff0000u);
#pragma unroll
      for (int s = 0; s < S_; ++s) {
        const float4 qa = *(const float4*)&qs[s][j * 8];
        const float4 qb = *(const float4*)&qs[s][j * 8 + 4];
        lg[s] += qa.x * kf[0] + qa.y * kf[1] + qa.z * kf[2] + qa.w * kf[3]
               + qb.x * kf[4] + qb.y * kf[5] + qb.z * kf[6] + qb.w * kf[7];
      }
    }
    float mx = -1e30f;
#pragma unroll
    for (int s = 0; s < S_; ++s) { lg[s] *= 0.125f; mx = fmaxf(mx, lg[s]); }
    float es[S_], sum = 0.f;
#pragma unroll
    for (int s = 0; s < S_; ++s) { es[s] = __expf(lg[s] - mx); sum += es[s]; }
    const float inv = 1.f / sum;
    float d7[S_];
#pragma unroll
    for (int s = 0; s < S_; ++s) {
      const float wv_ = es[s] * inv;
      wl[s][tid] = wv_;
      d7[s] = wv_;
    }
    // wave-reduce denominator partials (sum over this wave's 64 n)
#pragma unroll
    for (int s = 0; s < S_; ++s) {
#pragma unroll
      for (int o = 32; o >= 1; o >>= 1) d7[s] += __shfl_xor(d7[s], o);
    }
    if (ln == 0) {
#pragma unroll
      for (int s = 0; s < S_; ++s) partd[wv][s] = d7[s];
    }
  }
  __syncthreads();

  // phase 2: wave wv accumulates its own 64 nn for ALL 7 s; 2 nn per iter
  {
    const unsigned short* vptr = kv + ((size_t)(b * N_ + cb * NC_ + wv * 64)) * 128 + 64 + ln;
    float acc[S_];
#pragma unroll
    for (int s = 0; s < S_; ++s) acc[s] = 0.f;
#pragma unroll 4
    for (int nn2 = 0; nn2 < 32; ++nn2) {
      const int nn = nn2 * 2;
      const float v0 = bf2f(vptr[(size_t)nn * 128]);
      const float v1 = bf2f(vptr[(size_t)nn * 128 + 128]);
#pragma unroll
      for (int s = 0; s < S_; ++s) {
        const float2 w2 = *(const float2*)&wl[s][wv * 64 + nn];
        acc[s] += w2.x * v0 + w2.y * v1;
      }
    }
#pragma unroll
    for (int s = 0; s < S_; ++s) part[wv][s][ln] = acc[s];
  }
  __syncthreads();

  // cross-wave reduce -> global partials (448 outputs, strided loop!)
  for (int p = tid; p < S_ * 64; p += 256) {
    const int s = p >> 6, d = p & 63;
    const float sum4 = part[0][s][d] + part[1][s][d] + part[2][s][d] + part[3][s][d];
    numer[((size_t)(b * NB_ + cb) * S_ + s) * 64 + d] = sum4;
  }
  if (tid < S_) {
    denom[(b * NB_ + cb) * S_ + tid] =
        partd[0][tid] + partd[1][tid] + partd[2][tid] + partd[3][tid];
  }
}

// ---------------- K3: reduce partials + GRU + MLP + next q -----------------
__global__ __launch_bounds__(192) void update_kernel(
    const float* __restrict__ numer, const float* __restrict__ denom,
    const float* __restrict__ Wih, const float* __restrict__ Whh,
    const float* __restrict__ bih, const float* __restrict__ bhh,
    const float* __restrict__ g_mlp, const float* __restrict__ b_mlp,
    const float* __restrict__ W1, const float* __restrict__ b1,
    const float* __restrict__ W2, const float* __restrict__ b2,
    const float* __restrict__ g_sl, const float* __restrict__ b_sl,
    const float* __restrict__ Wq,
    float* __restrict__ sl_ws, float* __restrict__ q_ws,
    float* __restrict__ d_out, const int write_out) {
  const int bs = blockIdx.x;
  const int b = bs / S_, s = bs % S_;
  const int tid = threadIdx.x;
  __shared__ float attn[64], sl[64], gi[192], gh[192], hn[64], h1[128], sn[64], tmp[64];

  if (tid < 64) {
    float acc = 0.f, dd = 0.f;
#pragma unroll 8
    for (int blk = 0; blk < NB_; ++blk) {
      acc += numer[((size_t)(b * NB_ + blk) * S_ + s) * 64 + tid];
      dd += denom[(b * NB_ + blk) * S_ + s];
    }
    attn[tid] = acc / (dd + 1e-12f);
    sl[tid] = sl_ws[bs * 64 + tid];
  }
  __syncthreads();
  {
    float a = bih[tid], h = bhh[tid];
    const float* wi = Wih + tid * 64;
    const float* wh = Whh + tid * 64;
#pragma unroll 8
    for (int d = 0; d < 64; ++d) { a += attn[d] * wi[d]; h += sl[d] * wh[d]; }
    gi[tid] = a; gh[tid] = h;
  }
  __syncthreads();
  if (tid < 64) {
    const float r = 1.f / (1.f + __expf(-(gi[tid] + gh[tid])));
    const float z = 1.f / (1.f + __expf(-(gi[64 + tid] + gh[64 + tid])));
    const float nn = tanhf(gi[128 + tid] + r * gh[128 + tid]);
    sn[tid] = (1.f - z) * nn + z * sl[tid];
  }
  __syncthreads();
  if (tid < 64) {  // LN(sn) with g_mlp/b_mlp
    const float v = sn[tid];
    float su = v, sq = v * v;
#pragma unroll
    for (int o = 32; o >= 1; o >>= 1) { su += __shfl_xor(su, o); sq += __shfl_xor(sq, o); }
    const float mean = su * (1.f / 64.f);
    const float rstd = rsqrtf(fmaxf(sq * (1.f / 64.f) - mean * mean, 0.f) + 1e-5f);
    hn[tid] = (v - mean) * rstd * g_mlp[tid] + b_mlp[tid];
  }
  __syncthreads();
  if (tid < 128) {
    float a = b1[tid];
    const float* w1r = W1 + tid * 64;
#pragma unroll 8
    for (int d = 0; d < 64; ++d) a += hn[d] * w1r[d];
    h1[tid] = fmaxf(a, 0.f);
  }
  __syncthreads();
  if (tid < 64) {
    float a = b2[tid];
    const float* w2r = W2 + tid * 128;
#pragma unroll 8
    for (int h = 0; h < 128; ++h) a += h1[h] * w2r[h];
    const float o = sn[tid] + a;
    sl_ws[bs * 64 + tid] = o;
    if (write_out) d_out[bs * 64 + tid] = o;
    tmp[tid] = o;
  }
  __syncthreads();
  if (tid < 64) {  // LN(new slots) with g_sl/b_sl for next q
    const float v = tmp[tid];
    float su = v, sq = v * v;
#pragma unroll
    for (int o = 32; o >= 1; o >>= 1) { su += __shfl_xor(su, o); sq += __shfl_xor(sq, o); }
    const float mean = su * (1.f / 64.f);
    const float rstd = rsqrtf(fmaxf(sq * (1.f / 64.f) - mean * mean, 0.f) + 1e-5f);
    hn[tid] = (v - mean) * rstd * g_sl[tid] + b_sl[tid];
  }
  __syncthreads();
  if (tid < 64) {
    float a = 0.f;
    const float* wq = Wq + tid * 64;
#pragma unroll 8
    for (int d = 0; d < 64; ++d) a += hn[d] * wq[d];
    q_ws[bs * 64 + tid] = a;
  }
}

extern "C" void kernel_launch(void* const* d_in, const int* in_sizes, int n_in,
                              void* d_out, int out_size, void* d_ws, size_t ws_size,
                              hipStream_t stream) {
  const float* x = (const float*)d_in[0];
  const float* slots = (const float*)d_in[1];
  const float* g_in = (const float*)d_in[2];
  const float* b_in = (const float*)d_in[3];
  const float* g_sl = (const float*)d_in[4];
  const float* b_sl = (const float*)d_in[5];
  const float* g_mlp = (const float*)d_in[6];
  const float* b_mlp = (const float*)d_in[7];
  const float* Wq = (const float*)d_in[8];
  const float* Wkv = (const float*)d_in[9];
  const float* Wih = (const float*)d_in[10];
  const float* Whh = (const float*)d_in[11];
  const float* bih = (const float*)d_in[12];
  const float* bhh = (const float*)d_in[13];
  const float* W1 = (const float*)d_in[14];
  const float* b1 = (const float*)d_in[15];
  const float* W2 = (const float*)d_in[16];
  const float* b2 = (const float*)d_in[17];

  char* ws = (char*)d_ws;
  size_t off = 0;
  unsigned short* kv = (unsigned short*)(ws + off); off += (size_t)B_ * N_ * 128 * 2;  // 32 MB
  uint4* Wbf = (uint4*)(ws + off); off += 65536;
  float* q_ws = (float*)(ws + off); off += (size_t)B_ * S_ * D_ * 4;
  float* sl_ws = (float*)(ws + off); off += (size_t)B_ * S_ * D_ * 4;
  float* numer = (float*)(ws + off); off += (size_t)B_ * NB_ * S_ * D_ * 4;
  float* denom = (float*)(ws + off); off += (size_t)B_ * NB_ * S_ * 4;

  prep_kernel<<<16 + B_ * S_, 256, 0, stream>>>(Wkv, Wbf, slots, g_sl, b_sl, Wq, sl_ws, q_ws);
  kv_kernel<<<(B_ * N_) / 64, 256, 0, stream>>>(x, g_in, b_in, Wbf, kv);
  for (int it = 0; it < 3; ++it) {
    attn_kernel<<<dim3(NB_, B_), 256, 0, stream>>>(kv, q_ws, numer, denom);
    update_kernel<<<B_ * S_, 192, 0, stream>>>(numer, denom, Wih, Whh, bih, bhh,
                                               g_mlp, b_mlp, W1, b1, W2, b2, g_sl, b_sl, Wq,
                                               sl_ws, q_ws, (float*)d_out, it == 2 ? 1 : 0);
  }
}

// Round 7
// 108.946 us; speedup vs baseline: 1.0682x; 1.0581x over previous
//
#include <hip/hip_runtime.h>
#include <hip/hip_bf16.h>
#include <stdint.h>

#define B_ 32
#define N_ 4096
#define C_ 256
#define S_ 7
#define D_ 64
#define H_ 128
#define NB_ 8      // n-chunks per batch in attention
#define NC_ 512    // chunk size (NB_*NC_ == N_)

typedef __attribute__((ext_vector_type(8))) short short8;
typedef __attribute__((ext_vector_type(4))) float f32x4;

// Native f32->bf16 RNE: compiler emits v_cvt_pk_bf16_f32 (m240: casts beat
// hand-rolled bit-ops, which block the cvt_pk path).
static __device__ __forceinline__ unsigned short f2bf(float f) {
  __hip_bfloat16 h = __float2bfloat16(f);
  return *reinterpret_cast<unsigned short*>(&h);
}
static __device__ __forceinline__ float bf2f(unsigned short h) {
  return __uint_as_float(((unsigned int)h) << 16);
}

// ---------------- prep: pack Wkv into MFMA B-fragments + init slots/q0 -----
__global__ __launch_bounds__(256) void prep_kernel(
    const float* __restrict__ Wkv, uint4* __restrict__ Wbf,
    const float* __restrict__ slots, const float* __restrict__ g_sl,
    const float* __restrict__ b_sl, const float* __restrict__ Wq,
    float* __restrict__ sl_ws, float* __restrict__ q_ws) {
  __shared__ float hl[64];
  if (blockIdx.x < 16) {
    const int t = blockIdx.x * 256 + threadIdx.x;   // 0..4095
    const int f = t >> 6, lane = t & 63;
    const int e = ((f >> 3) << 4) + (lane & 15);
    const int c = ((f & 7) << 5) + ((lane >> 4) << 3);
    const float* src = Wkv + e * 256 + c;
    uint4 o;
    o.x = f2bf(src[0]) | ((unsigned)f2bf(src[1]) << 16);
    o.y = f2bf(src[2]) | ((unsigned)f2bf(src[3]) << 16);
    o.z = f2bf(src[4]) | ((unsigned)f2bf(src[5]) << 16);
    o.w = f2bf(src[6]) | ((unsigned)f2bf(src[7]) << 16);
    Wbf[t] = o;
  } else {
    const int bs = blockIdx.x - 16;                 // 0..223
    const int tid = threadIdx.x;
    if (tid < 64) {
      const float v = slots[bs * 64 + tid];
      sl_ws[bs * 64 + tid] = v;
      float su = v, sq = v * v;
#pragma unroll
      for (int o = 32; o >= 1; o >>= 1) { su += __shfl_xor(su, o); sq += __shfl_xor(sq, o); }
      const float mean = su * (1.f / 64.f);
      const float rstd = rsqrtf(fmaxf(sq * (1.f / 64.f) - mean * mean, 0.f) + 1e-5f);
      hl[tid] = (v - mean) * rstd * g_sl[tid] + b_sl[tid];
    }
    __syncthreads();
    if (tid < 64) {
      float acc = 0.f;
      const float* wq = Wq + tid * 64;
#pragma unroll 8
      for (int d = 0; d < 64; ++d) acc += hl[d] * wq[d];
      q_ws[bs * 64 + tid] = acc;
    }
  }
}

// ---------------- K_KV: fused LayerNorm(x) + GEMM -> kv (bf16) -------------
// r3 structure (proven): unroll 2 on LN loop, 32 KiB LDS, 4 blk/CU.
// Only change vs r3: f2bf uses native cvt (see above).
__global__ __launch_bounds__(256, 4) void kv_kernel(
    const float* __restrict__ x, const float* __restrict__ g_in,
    const float* __restrict__ b_in, const uint4* __restrict__ Wbf,
    unsigned short* __restrict__ kv) {
  __shared__ __align__(16) char lds[32768];
  const int tid = threadIdx.x;
  const int lane = tid & 63, w = tid >> 6;
  const int wm = w >> 1, wn = w & 1;
  const size_t rowbase = (size_t)blockIdx.x * 64;

  {
    const int q = lane & 15, grp = lane >> 4;
    float4 gv[4], bv[4];
#pragma unroll
    for (int j = 0; j < 4; ++j) {
      gv[j] = *(const float4*)(g_in + j * 64 + q * 4);
      bv[j] = *(const float4*)(b_in + j * 64 + q * 4);
    }
#pragma unroll 2
    for (int i = 0; i < 4; ++i) {
      const int r = w * 16 + i * 4 + grp;
      const float* xrow = x + (rowbase + r) * 256;
      float4 xv[4];
#pragma unroll
      for (int j = 0; j < 4; ++j) xv[j] = *(const float4*)(xrow + j * 64 + q * 4);
      float su = 0.f, sq = 0.f;
#pragma unroll
      for (int j = 0; j < 4; ++j) {
        su += xv[j].x + xv[j].y + xv[j].z + xv[j].w;
        sq += xv[j].x * xv[j].x + xv[j].y * xv[j].y + xv[j].z * xv[j].z + xv[j].w * xv[j].w;
      }
#pragma unroll
      for (int o = 8; o >= 1; o >>= 1) { su += __shfl_xor(su, o); sq += __shfl_xor(sq, o); }
      const float mean = su * (1.f / 256.f);
      const float rstd = rsqrtf(fmaxf(sq * (1.f / 256.f) - mean * mean, 0.f) + 1e-5f);
#pragma unroll
      for (int j = 0; j < 4; ++j) {
        const float n0 = (xv[j].x - mean) * rstd * gv[j].x + bv[j].x;
        const float n1 = (xv[j].y - mean) * rstd * gv[j].y + bv[j].y;
        const float n2 = (xv[j].z - mean) * rstd * gv[j].z + bv[j].z;
        const float n3 = (xv[j].w - mean) * rstd * gv[j].w + bv[j].w;
        uint2 pk;
        pk.x = (unsigned)f2bf(n0) | ((unsigned)f2bf(n1) << 16);
        pk.y = (unsigned)f2bf(n2) | ((unsigned)f2bf(n3) << 16);
        const int addr = (r * 512 + j * 128 + q * 8) ^ ((r & 7) << 4);   // XOR swizzle
        *(uint2*)(lds + addr) = pk;
      }
    }
  }
  __syncthreads();

  f32x4 acc[2][4];
#pragma unroll
  for (int m = 0; m < 2; ++m)
#pragma unroll
    for (int n = 0; n < 4; ++n) acc[m][n] = (f32x4){0.f, 0.f, 0.f, 0.f};

#pragma unroll
  for (int ks = 0; ks < 8; ++ks) {
    short8 a[2];
#pragma unroll
    for (int m = 0; m < 2; ++m) {
      const int row = wm * 32 + m * 16 + (lane & 15);
      const int addr = (row * 512 + ks * 64 + ((lane >> 4) << 4)) ^ ((row & 7) << 4);
      a[m] = *(const short8*)(lds + addr);
    }
#pragma unroll
    for (int n = 0; n < 4; ++n) {
      union { uint4 u; short8 s; } wb;
      wb.u = Wbf[((wn * 4 + n) * 8 + ks) * 64 + lane];
#pragma unroll
      for (int m = 0; m < 2; ++m)
        acc[m][n] = __builtin_amdgcn_mfma_f32_16x16x32_bf16(a[m], wb.s, acc[m][n], 0, 0, 0);
    }
  }
  __syncthreads();

  // epilogue: C/D layout col=lane&15, row=(lane>>4)*4+j -> padded LDS -> coalesced store
#pragma unroll
  for (int m = 0; m < 2; ++m)
#pragma unroll
    for (int n = 0; n < 4; ++n) {
      const int row0 = wm * 32 + m * 16 + ((lane >> 4) << 2);
      const int col = wn * 64 + n * 16 + (lane & 15);
#pragma unroll
      for (int j = 0; j < 4; ++j)
        *(unsigned short*)(lds + (row0 + j) * 264 + col * 2) = f2bf(acc[m][n][j]);
    }
  __syncthreads();
#pragma unroll
  for (int i = 0; i < 16; ++i) {
    const int r = w * 16 + i;
    const unsigned int vv = *(const unsigned int*)(lds + r * 264 + lane * 4);
    *(unsigned int*)((char*)kv + (rowbase + r) * 256 + lane * 4) = vv;
  }
}

// ---------------- K2: fused logits/softmax(S)/weighted-sum partials --------
// EXACT r3 version (proven fastest attn): 512 threads (8 waves). phase1:
// thread = one n, proper softmax over s. phase2: wave owns 64 nn, all 7 s.
__global__ __launch_bounds__(512) void attn_kernel(
    const unsigned short* __restrict__ kv, const float* __restrict__ q_ws,
    float* __restrict__ numer, float* __restrict__ denom) {
  __shared__ float qs[S_][64];
  __shared__ float wl[S_][NC_];
  __shared__ float part[8][S_][64];
  __shared__ float partd[8][S_];
  const int b = blockIdx.y, cb = blockIdx.x;
  const int tid = threadIdx.x;
  if (tid < S_ * 64) qs[tid >> 6][tid & 63] = q_ws[b * S_ * 64 + tid];
  __syncthreads();

  const int n = cb * NC_ + tid;
  const unsigned short* krow = kv + ((size_t)(b * N_ + n)) * 128;
  float lg[S_];
#pragma unroll
  for (int s = 0; s < S_; ++s) lg[s] = 0.f;
#pragma unroll
  for (int j = 0; j < 8; ++j) {
    const uint4 kk = *(const uint4*)(krow + j * 8);
    float kf[8];
    kf[0] = __uint_as_float(kk.x << 16); kf[1] = __uint_as_float(kk.x & 0xffff0000u);
    kf[2] = __uint_as_float(kk.y << 16); kf[3] = __uint_as_float(kk.y & 0xffff0000u);
    kf[4] = __uint_as_float(kk.z << 16); kf[5] = __uint_as_float(kk.z & 0xffff0000u);
    kf[6] = __uint_as_float(kk.w << 16); kf[7] = __uint_as_float(kk.w & 0xffff0000u);
#pragma unroll
    for (int s = 0; s < S_; ++s) {
      const float4 qa = *(const float4*)&qs[s][j * 8];
      const float4 qb = *(const float4*)&qs[s][j * 8 + 4];
      lg[s] += qa.x * kf[0] + qa.y * kf[1] + qa.z * kf[2] + qa.w * kf[3]
             + qb.x * kf[4] + qb.y * kf[5] + qb.z * kf[6] + qb.w * kf[7];
    }
  }
  float mx = -1e30f;
#pragma unroll
  for (int s = 0; s < S_; ++s) { lg[s] *= 0.125f; mx = fmaxf(mx, lg[s]); }
  float es[S_], sum = 0.f;
#pragma unroll
  for (int s = 0; s < S_; ++s) { es[s] = __expf(lg[s] - mx); sum += es[s]; }
  const float inv = 1.f / sum;   // proper softmax over s
#pragma unroll
  for (int s = 0; s < S_; ++s) wl[s][tid] = es[s] * inv;
  __syncthreads();

  const int wv = tid >> 6, ln = tid & 63;
  {
    const unsigned short* vptr = kv + ((size_t)(b * N_ + cb * NC_ + wv * 64)) * 128 + 64 + ln;
    float acc[S_], ds[S_];
#pragma unroll
    for (int s = 0; s < S_; ++s) { acc[s] = 0.f; ds[s] = 0.f; }
#pragma unroll 8
    for (int nn = 0; nn < 64; ++nn) {
      const float vv = bf2f(vptr[(size_t)nn * 128]);
#pragma unroll
      for (int s = 0; s < S_; ++s) {
        const float wgt = wl[s][wv * 64 + nn];
        acc[s] += wgt * vv;
        ds[s] += wgt;
      }
    }
#pragma unroll
    for (int s = 0; s < S_; ++s) part[wv][s][ln] = acc[s];
    if (ln == 0) {
#pragma unroll
      for (int s = 0; s < S_; ++s) partd[wv][s] = ds[s];
    }
  }
  __syncthreads();

  if (tid < S_ * 64) {
    const int s = tid >> 6, d = tid & 63;
    float sum8 = 0.f;
#pragma unroll
    for (int wvi = 0; wvi < 8; ++wvi) sum8 += part[wvi][s][d];
    numer[((size_t)(b * NB_ + cb) * S_ + s) * 64 + d] = sum8;
  }
  if (tid < S_) {
    float sd = 0.f;
#pragma unroll
    for (int wvi = 0; wvi < 8; ++wvi) sd += partd[wvi][tid];
    denom[(b * NB_ + cb) * S_ + tid] = sd;
  }
}

// ---------------- K3: reduce partials + GRU + MLP + next q -----------------
__global__ __launch_bounds__(192) void update_kernel(
    const float* __restrict__ numer, const float* __restrict__ denom,
    const float* __restrict__ Wih, const float* __restrict__ Whh,
    const float* __restrict__ bih, const float* __restrict__ bhh,
    const float* __restrict__ g_mlp, const float* __restrict__ b_mlp,
    const float* __restrict__ W1, const float* __restrict__ b1,
    const float* __restrict__ W2, const float* __restrict__ b2,
    const float* __restrict__ g_sl, const float* __restrict__ b_sl,
    const float* __restrict__ Wq,
    float* __restrict__ sl_ws, float* __restrict__ q_ws,
    float* __restrict__ d_out, const int write_out) {
  const int bs = blockIdx.x;
  const int b = bs / S_, s = bs % S_;
  const int tid = threadIdx.x;
  __shared__ float attn[64], sl[64], gi[192], gh[192], hn[64], h1[128], sn[64], tmp[64];

  if (tid < 64) {
    float acc = 0.f, dd = 0.f;
#pragma unroll
    for (int blk = 0; blk < NB_; ++blk) {
      acc += numer[((size_t)(b * NB_ + blk) * S_ + s) * 64 + tid];
      dd += denom[(b * NB_ + blk) * S_ + s];
    }
    attn[tid] = acc / (dd + 1e-12f);
    sl[tid] = sl_ws[bs * 64 + tid];
  }
  __syncthreads();
  {
    float a = bih[tid], h = bhh[tid];
    const float* wi = Wih + tid * 64;
    const float* wh = Whh + tid * 64;
#pragma unroll 8
    for (int d = 0; d < 64; ++d) { a += attn[d] * wi[d]; h += sl[d] * wh[d]; }
    gi[tid] = a; gh[tid] = h;
  }
  __syncthreads();
  if (tid < 64) {
    const float r = 1.f / (1.f + __expf(-(gi[tid] + gh[tid])));
    const float z = 1.f / (1.f + __expf(-(gi[64 + tid] + gh[64 + tid])));
    const float nn = tanhf(gi[128 + tid] + r * gh[128 + tid]);
    sn[tid] = (1.f - z) * nn + z * sl[tid];
  }
  __syncthreads();
  if (tid < 64) {  // LN(sn) with g_mlp/b_mlp
    const float v = sn[tid];
    float su = v, sq = v * v;
#pragma unroll
    for (int o = 32; o >= 1; o >>= 1) { su += __shfl_xor(su, o); sq += __shfl_xor(sq, o); }
    const float mean = su * (1.f / 64.f);
    const float rstd = rsqrtf(fmaxf(sq * (1.f / 64.f) - mean * mean, 0.f) + 1e-5f);
    hn[tid] = (v - mean) * rstd * g_mlp[tid] + b_mlp[tid];
  }
  __syncthreads();
  if (tid < 128) {
    float a = b1[tid];
    const float* w1r = W1 + tid * 64;
#pragma unroll 8
    for (int d = 0; d < 64; ++d) a += hn[d] * w1r[d];
    h1[tid] = fmaxf(a, 0.f);
  }
  __syncthreads();
  if (tid < 64) {
    float a = b2[tid];
    const float* w2r = W2 + tid * 128;
#pragma unroll 8
    for (int h = 0; h < 128; ++h) a += h1[h] * w2r[h];
    const float o = sn[tid] + a;
    sl_ws[bs * 64 + tid] = o;
    if (write_out) d_out[bs * 64 + tid] = o;
    tmp[tid] = o;
  }
  __syncthreads();
  if (tid < 64) {  // LN(new slots) with g_sl/b_sl for next q
    const float v = tmp[tid];
    float su = v, sq = v * v;
#pragma unroll
    for (int o = 32; o >= 1; o >>= 1) { su += __shfl_xor(su, o); sq += __shfl_xor(sq, o); }
    const float mean = su * (1.f / 64.f);
    const float rstd = rsqrtf(fmaxf(sq * (1.f / 64.f) - mean * mean, 0.f) + 1e-5f);
    hn[tid] = (v - mean) * rstd * g_sl[tid] + b_sl[tid];
  }
  __syncthreads();
  if (tid < 64) {
    float a = 0.f;
    const float* wq = Wq + tid * 64;
#pragma unroll 8
    for (int d = 0; d < 64; ++d) a += hn[d] * wq[d];
    q_ws[bs * 64 + tid] = a;
  }
}

extern "C" void kernel_launch(void* const* d_in, const int* in_sizes, int n_in,
                              void* d_out, int out_size, void* d_ws, size_t ws_size,
                              hipStream_t stream) {
  const float* x = (const float*)d_in[0];
  const float* slots = (const float*)d_in[1];
  const float* g_in = (const float*)d_in[2];
  const float* b_in = (const float*)d_in[3];
  const float* g_sl = (const float*)d_in[4];
  const float* b_sl = (const float*)d_in[5];
  const float* g_mlp = (const float*)d_in[6];
  const float* b_mlp = (const float*)d_in[7];
  const float* Wq = (const float*)d_in[8];
  const float* Wkv = (const float*)d_in[9];
  const float* Wih = (const float*)d_in[10];
  const float* Whh = (const float*)d_in[11];
  const float* bih = (const float*)d_in[12];
  const float* bhh = (const float*)d_in[13];
  const float* W1 = (const float*)d_in[14];
  const float* b1 = (const float*)d_in[15];
  const float* W2 = (const float*)d_in[16];
  const float* b2 = (const float*)d_in[17];

  char* ws = (char*)d_ws;
  size_t off = 0;
  unsigned short* kv = (unsigned short*)(ws + off); off += (size_t)B_ * N_ * 128 * 2;  // 32 MB
  uint4* Wbf = (uint4*)(ws + off); off += 65536;
  float* q_ws = (float*)(ws + off); off += (size_t)B_ * S_ * D_ * 4;
  float* sl_ws = (float*)(ws + off); off += (size_t)B_ * S_ * D_ * 4;
  float* numer = (float*)(ws + off); off += (size_t)B_ * NB_ * S_ * D_ * 4;
  float* denom = (float*)(ws + off); off += (size_t)B_ * NB_ * S_ * 4;

  prep_kernel<<<16 + B_ * S_, 256, 0, stream>>>(Wkv, Wbf, slots, g_sl, b_sl, Wq, sl_ws, q_ws);
  kv_kernel<<<(B_ * N_) / 64, 256, 0, stream>>>(x, g_in, b_in, Wbf, kv);
  for (int it = 0; it < 3; ++it) {
    attn_kernel<<<dim3(NB_, B_), NC_, 0, stream>>>(kv, q_ws, numer, denom);
    update_kernel<<<B_ * S_, 192, 0, stream>>>(numer, denom, Wih, Whh, bih, bhh,
                                               g_mlp, b_mlp, W1, b1, W2, b2, g_sl, b_sl, Wq,
                                               sl_ws, q_ws, (float*)d_out, it == 2 ? 1 : 0);
  }
}